// Round 1
// baseline (413.209 us; speedup 1.0000x reference)
//
#include <hip/hip_runtime.h>
#include <hip/hip_bf16.h>

// PartitionedNormalization: per-domain BN stats (training mode) + affine.
// inputs: x[B][128] f32, global_gamma[128], global_beta[128],
//         domain_gamma[8][128], domain_beta[8][128], domain_index[B] i32
// out[B][128] f32 = (gg+dg[s])*(x-mean[s])*rsqrt(var[s]+eps) + (gb+db[s])

#define DIM 128
#define NDOM 8
#define PENT (NDOM + 2 * NDOM * DIM)  // 8 counts + 1024 sums + 1024 sqsums = 2056
#define EPSV 1e-3f

// ---------------- pass 1: per-block partial sums ----------------
__global__ __launch_bounds__(256) void pn_reduce(const float* __restrict__ x,
                                                 const int* __restrict__ seg,
                                                 float* __restrict__ partials,
                                                 int rowsPerBlock) {
  __shared__ float ls[NDOM * DIM];  // sums
  __shared__ float lq[NDOM * DIM];  // sqsums
  __shared__ float lc[NDOM];        // counts
  const int tid = threadIdx.x;
  for (int i = tid; i < NDOM * DIM; i += 256) { ls[i] = 0.f; lq[i] = 0.f; }
  if (tid < NDOM) lc[tid] = 0.f;
  __syncthreads();

  const int col = tid & (DIM - 1);
  const int rowOff = tid >> 7;  // 0 or 1 (256 threads cover 2 rows)
  const int base = blockIdx.x * rowsPerBlock;

  // 8 rows per iteration: rows base+r .. base+r+7; this thread does 4 of them.
  for (int r = 0; r < rowsPerBlock; r += 8) {
    const int r0 = base + r + rowOff;
    const int s0 = seg[r0];
    const int s1 = seg[r0 + 2];
    const int s2 = seg[r0 + 4];
    const int s3 = seg[r0 + 6];
    const float x0 = x[r0 * DIM + col];
    const float x1 = x[(r0 + 2) * DIM + col];
    const float x2 = x[(r0 + 4) * DIM + col];
    const float x3 = x[(r0 + 6) * DIM + col];
    atomicAdd(&ls[s0 * DIM + col], x0);
    atomicAdd(&lq[s0 * DIM + col], x0 * x0);
    atomicAdd(&ls[s1 * DIM + col], x1);
    atomicAdd(&lq[s1 * DIM + col], x1 * x1);
    atomicAdd(&ls[s2 * DIM + col], x2);
    atomicAdd(&lq[s2 * DIM + col], x2 * x2);
    atomicAdd(&ls[s3 * DIM + col], x3);
    atomicAdd(&lq[s3 * DIM + col], x3 * x3);
    if (col == 0) {
      atomicAdd(&lc[s0], 1.f);
      atomicAdd(&lc[s1], 1.f);
      atomicAdd(&lc[s2], 1.f);
      atomicAdd(&lc[s3], 1.f);
    }
  }
  __syncthreads();

  float* outp = partials + (size_t)blockIdx.x * PENT;
  if (tid < NDOM) outp[tid] = lc[tid];
  for (int i = tid; i < NDOM * DIM; i += 256) {
    outp[NDOM + i] = ls[i];
    outp[NDOM + NDOM * DIM + i] = lq[i];
  }
}

// ---------------- pass 2a: reduce NB partial rows -> 64 ----------------
__global__ __launch_bounds__(256) void pn_reduce2(const float* __restrict__ partials,
                                                  float* __restrict__ partials2,
                                                  int NB) {
  const int b = blockIdx.x;        // 0..63
  const int per = NB >> 6;         // NB is pow2 >= 64
  const int b0 = b * per;
  const int tid = threadIdx.x;
  float acc[9];
#pragma unroll
  for (int i = 0; i < 9; ++i) acc[i] = 0.f;
  for (int j = b0; j < b0 + per; ++j) {
    const float* p = partials + (size_t)j * PENT;
#pragma unroll
    for (int i = 0; i < 9; ++i) {
      const int e = tid + i * 256;
      if (e < PENT) acc[i] += p[e];
    }
  }
  float* o = partials2 + (size_t)b * PENT;
#pragma unroll
  for (int i = 0; i < 9; ++i) {
    const int e = tid + i * 256;
    if (e < PENT) o[e] = acc[i];
  }
}

// ---------------- pass 2b: final reduce + scale/shift table ----------------
__global__ __launch_bounds__(1024) void pn_finalize(const float* __restrict__ partials2,
                                                    const float* __restrict__ gg,
                                                    const float* __restrict__ gb,
                                                    const float* __restrict__ dg,
                                                    const float* __restrict__ db,
                                                    float* __restrict__ stats) {
  __shared__ float cnt[NDOM];
  const int t = threadIdx.x;  // 0..1023 -> (k = t>>7, d = t&127)
  if (t < NDOM) {
    float c = 0.f;
    for (int j = 0; j < 64; ++j) c += partials2[(size_t)j * PENT + t];
    cnt[t] = fmaxf(c, 1.f);
  }
  __syncthreads();
  float s = 0.f, q = 0.f;
  for (int j = 0; j < 64; ++j) {
    const float* p = partials2 + (size_t)j * PENT;
    s += p[NDOM + t];
    q += p[NDOM + NDOM * DIM + t];
  }
  const int k = t >> 7;
  const int d = t & (DIM - 1);
  const float n = cnt[k];
  const float mean = s / n;
  const float var = fmaxf(q / n - mean * mean, 0.f);
  const float rstd = rsqrtf(var + EPSV);
  const float scale = (gg[d] + dg[t]) * rstd;         // dg[k*128+d] == dg[t]
  const float shift = (gb[d] + db[t]) - scale * mean;
  stats[t] = scale;
  stats[NDOM * DIM + t] = shift;
}

// ---------------- pass 3: normalize ----------------
__global__ __launch_bounds__(256) void pn_apply(const float* __restrict__ x,
                                                const int* __restrict__ seg,
                                                const float* __restrict__ stats,
                                                float* __restrict__ out) {
  const int g = blockIdx.x * 256 + threadIdx.x;  // float4 index
  const int row = g >> 5;                        // 32 float4 per row
  const int c4 = g & 31;
  const int s = seg[row];
  const float4 xv = ((const float4*)x)[g];
  const float4 a = ((const float4*)(stats + s * DIM))[c4];
  const float4 b = ((const float4*)(stats + NDOM * DIM + s * DIM))[c4];
  float4 o;
  o.x = fmaf(xv.x, a.x, b.x);
  o.y = fmaf(xv.y, a.y, b.y);
  o.z = fmaf(xv.z, a.z, b.z);
  o.w = fmaf(xv.w, a.w, b.w);
  ((float4*)out)[g] = o;
}

extern "C" void kernel_launch(void* const* d_in, const int* in_sizes, int n_in,
                              void* d_out, int out_size, void* d_ws, size_t ws_size,
                              hipStream_t stream) {
  const float* x = (const float*)d_in[0];
  const float* gg = (const float*)d_in[1];
  const float* gb = (const float*)d_in[2];
  const float* dg = (const float*)d_in[3];
  const float* db = (const float*)d_in[4];
  const int* seg = (const int*)d_in[5];
  float* out = (float*)d_out;

  const int B = in_sizes[5];  // 262144

  // workspace layout: partials[NB][2056] | partials2[64][2056] | stats[2048]
  int NB = 1024;
  while (NB > 64 &&
         ((size_t)NB * PENT + 64 * PENT + 2 * NDOM * DIM) * sizeof(float) > ws_size)
    NB >>= 1;
  float* partials = (float*)d_ws;
  float* partials2 = partials + (size_t)NB * PENT;
  float* stats = partials2 + (size_t)64 * PENT;

  const int rpb = B / NB;  // B = 2^18, NB pow2 -> exact, multiple of 8

  pn_reduce<<<NB, 256, 0, stream>>>(x, seg, partials, rpb);
  pn_reduce2<<<64, 256, 0, stream>>>(partials, partials2, NB);
  pn_finalize<<<1, 1024, 0, stream>>>(partials2, gg, gb, dg, db, stats);

  const int nblk = (B * (DIM / 4)) / 256;  // 32768
  pn_apply<<<nblk, 256, 0, stream>>>(x, seg, stats, out);
}

// Round 4
// 176.858 us; speedup vs baseline: 2.3364x; 2.3364x over previous
//
#include <hip/hip_runtime.h>
#include <hip/hip_bf16.h>

// PartitionedNormalization: per-domain BN stats (training mode) + affine.
// inputs: x[B][128] f32, global_gamma[128], global_beta[128],
//         domain_gamma[8][128], domain_beta[8][128], domain_index[B] i32
// out[B][128] f32 = (gg+dg[s])*(x-mean[s])*rsqrt(var[s]+eps) + (gb+db[s])

#define DIM 128
#define NDOM 8
#define PENT (NDOM + 2 * NDOM * DIM)  // 8 counts + 1024 sums + 1024 sqsums = 2056
#define EPSV 1e-3f

// ---------------- pass 1: register-accumulated per-block partial sums ----------------
// Thread t: column group c4 = t&31 (4 consecutive floats), row stream rsub = t>>5.
// 8 domains x (sum4 + sq4) accumulators live in registers (unrolled, const-indexed).
// LDS atomics only once per block at the end.
__global__ __launch_bounds__(256, 4) void pn_reduce(const float4* __restrict__ x4,
                                                    const int* __restrict__ seg,
                                                    float* __restrict__ partials,
                                                    int rowsPerBlock) {
  const int tid = threadIdx.x;
  const int c4 = tid & 31;   // float4 column index within row (32 per row)
  const int rsub = tid >> 5; // 0..7: 8 row streams per block
  const int base = blockIdx.x * rowsPerBlock;

  float4 sum[NDOM];
  float4 sq[NDOM];
  float cnt[NDOM];
#pragma unroll
  for (int k = 0; k < NDOM; ++k) {
    sum[k] = make_float4(0.f, 0.f, 0.f, 0.f);
    sq[k] = make_float4(0.f, 0.f, 0.f, 0.f);
    cnt[k] = 0.f;
  }

#pragma unroll 2
  for (int r = rsub; r < rowsPerBlock; r += 8) {
    const int row = base + r;
    const int s = seg[row];
    const float4 v = x4[(size_t)row * (DIM / 4) + c4];
    float4 vv;
    vv.x = v.x * v.x;
    vv.y = v.y * v.y;
    vv.z = v.z * v.z;
    vv.w = v.w * v.w;
#pragma unroll
    for (int k = 0; k < NDOM; ++k) {
      const float ind = (s == k) ? 1.f : 0.f;
      sum[k].x = fmaf(v.x, ind, sum[k].x);
      sum[k].y = fmaf(v.y, ind, sum[k].y);
      sum[k].z = fmaf(v.z, ind, sum[k].z);
      sum[k].w = fmaf(v.w, ind, sum[k].w);
      sq[k].x = fmaf(vv.x, ind, sq[k].x);
      sq[k].y = fmaf(vv.y, ind, sq[k].y);
      sq[k].z = fmaf(vv.z, ind, sq[k].z);
      sq[k].w = fmaf(vv.w, ind, sq[k].w);
      cnt[k] += ind;
    }
  }

  // -------- block-level reduce (once) --------
  __shared__ float ls[NDOM * DIM];
  __shared__ float lq[NDOM * DIM];
  __shared__ float lc[NDOM];
  for (int i = tid; i < NDOM * DIM; i += 256) { ls[i] = 0.f; lq[i] = 0.f; }
  if (tid < NDOM) lc[tid] = 0.f;
  __syncthreads();

  const int col = c4 * 4;
#pragma unroll
  for (int k = 0; k < NDOM; ++k) {
    atomicAdd(&ls[k * DIM + col + 0], sum[k].x);
    atomicAdd(&ls[k * DIM + col + 1], sum[k].y);
    atomicAdd(&ls[k * DIM + col + 2], sum[k].z);
    atomicAdd(&ls[k * DIM + col + 3], sum[k].w);
    atomicAdd(&lq[k * DIM + col + 0], sq[k].x);
    atomicAdd(&lq[k * DIM + col + 1], sq[k].y);
    atomicAdd(&lq[k * DIM + col + 2], sq[k].z);
    atomicAdd(&lq[k * DIM + col + 3], sq[k].w);
  }
  if (c4 == 0) {  // each row counted exactly once (by its c4==0 thread)
#pragma unroll
    for (int k = 0; k < NDOM; ++k) atomicAdd(&lc[k], cnt[k]);
  }
  __syncthreads();

  float* outp = partials + (size_t)blockIdx.x * PENT;
  if (tid < NDOM) outp[tid] = lc[tid];
  for (int i = tid; i < NDOM * DIM; i += 256) {
    outp[NDOM + i] = ls[i];
    outp[NDOM + NDOM * DIM + i] = lq[i];
  }
}

// ---------------- pass 2a: reduce NB partial rows -> 64 ----------------
__global__ __launch_bounds__(256) void pn_reduce2(const float* __restrict__ partials,
                                                  float* __restrict__ partials2,
                                                  int NB) {
  const int b = blockIdx.x;  // 0..63
  const int per = NB >> 6;   // NB is pow2 >= 64
  const int b0 = b * per;
  const int tid = threadIdx.x;
  float acc[9];
#pragma unroll
  for (int i = 0; i < 9; ++i) acc[i] = 0.f;
  for (int j = b0; j < b0 + per; ++j) {
    const float* p = partials + (size_t)j * PENT;
#pragma unroll
    for (int i = 0; i < 9; ++i) {
      const int e = tid + i * 256;
      if (e < PENT) acc[i] += p[e];
    }
  }
  float* o = partials2 + (size_t)b * PENT;
#pragma unroll
  for (int i = 0; i < 9; ++i) {
    const int e = tid + i * 256;
    if (e < PENT) o[e] = acc[i];
  }
}

// ---------------- pass 2b: final reduce + scale/shift table ----------------
__global__ __launch_bounds__(1024) void pn_finalize(const float* __restrict__ partials2,
                                                    const float* __restrict__ gg,
                                                    const float* __restrict__ gb,
                                                    const float* __restrict__ dg,
                                                    const float* __restrict__ db,
                                                    float* __restrict__ stats) {
  __shared__ float cnt[NDOM];
  const int t = threadIdx.x;  // 0..1023 -> (k = t>>7, d = t&127)
  if (t < NDOM) {
    float c = 0.f;
    for (int j = 0; j < 64; ++j) c += partials2[(size_t)j * PENT + t];
    cnt[t] = fmaxf(c, 1.f);
  }
  __syncthreads();
  float s = 0.f, q = 0.f;
  for (int j = 0; j < 64; ++j) {
    const float* p = partials2 + (size_t)j * PENT;
    s += p[NDOM + t];
    q += p[NDOM + NDOM * DIM + t];
  }
  const int k = t >> 7;
  const int d = t & (DIM - 1);
  const float n = cnt[k];
  const float mean = s / n;
  const float var = fmaxf(q / n - mean * mean, 0.f);
  const float rstd = rsqrtf(var + EPSV);
  const float scale = (gg[d] + dg[t]) * rstd;  // dg[k*128+d] == dg[t]
  const float shift = (gb[d] + db[t]) - scale * mean;
  stats[t] = scale;
  stats[NDOM * DIM + t] = shift;
}

// ---------------- pass 3: normalize ----------------
__global__ __launch_bounds__(256) void pn_apply(const float* __restrict__ x,
                                                const int* __restrict__ seg,
                                                const float* __restrict__ stats,
                                                float* __restrict__ out) {
  const int g = blockIdx.x * 256 + threadIdx.x;  // float4 index
  const int row = g >> 5;                        // 32 float4 per row
  const int c4 = g & 31;
  const int s = seg[row];
  const float4 xv = ((const float4*)x)[g];
  const float4 a = ((const float4*)(stats + s * DIM))[c4];
  const float4 b = ((const float4*)(stats + NDOM * DIM + s * DIM))[c4];
  float4 o;
  o.x = fmaf(xv.x, a.x, b.x);
  o.y = fmaf(xv.y, a.y, b.y);
  o.z = fmaf(xv.z, a.z, b.z);
  o.w = fmaf(xv.w, a.w, b.w);
  ((float4*)out)[g] = o;
}

extern "C" void kernel_launch(void* const* d_in, const int* in_sizes, int n_in,
                              void* d_out, int out_size, void* d_ws, size_t ws_size,
                              hipStream_t stream) {
  const float* x = (const float*)d_in[0];
  const float* gg = (const float*)d_in[1];
  const float* gb = (const float*)d_in[2];
  const float* dg = (const float*)d_in[3];
  const float* db = (const float*)d_in[4];
  const int* seg = (const int*)d_in[5];
  float* out = (float*)d_out;

  const int B = in_sizes[5];  // 262144

  // workspace layout: partials[NB][2056] | partials2[64][2056] | stats[2048]
  int NB = 1024;
  while (NB > 64 &&
         ((size_t)NB * PENT + 64 * PENT + 2 * NDOM * DIM) * sizeof(float) > ws_size)
    NB >>= 1;
  float* partials = (float*)d_ws;
  float* partials2 = partials + (size_t)NB * PENT;
  float* stats = partials2 + (size_t)64 * PENT;

  const int rpb = B / NB;  // B = 2^18, NB pow2 -> exact, multiple of 8

  pn_reduce<<<NB, 256, 0, stream>>>((const float4*)x, seg, partials, rpb);
  pn_reduce2<<<64, 256, 0, stream>>>(partials, partials2, NB);
  pn_finalize<<<1, 1024, 0, stream>>>(partials2, gg, gb, dg, db, stats);

  const int nblk = (B * (DIM / 4)) / 256;  // 32768
  pn_apply<<<nblk, 256, 0, stream>>>(x, seg, stats, out);
}

// Round 5
// 174.564 us; speedup vs baseline: 2.3671x; 1.0131x over previous
//
#include <hip/hip_runtime.h>
#include <hip/hip_bf16.h>

// PartitionedNormalization: per-domain BN stats (training mode) + affine.
// out[B][128] f32 = (gg+dg[s])*(x-mean[s])*rsqrt(var[s]+eps) + (gb+db[s])

#define DIM 128
#define NDOM 8
#define PENT (NDOM + 2 * NDOM * DIM)  // 8 counts + 1024 sums + 1024 sqsums = 2056
#define EPSV 1e-3f

// ---------------- pass 1: register-accumulated per-block partial sums ----------------
// Thread t: column group c4 = t&31 (one float4), row stream rsub = t>>5.
// 72 accumulators are NAMED SCALARS (no arrays -> guaranteed registers, rule #20;
// R4 showed float4 acc[8] spilled to scratch: VGPR=60, 134us latency-bound).
// launch_bounds(256,2): VGPR budget 256 so nothing spills.
__global__ __launch_bounds__(256, 2) void pn_reduce(const float4* __restrict__ x4,
                                                    const int* __restrict__ seg,
                                                    float* __restrict__ partials,
                                                    int rowsPerBlock) {
  const int tid = threadIdx.x;
  const int c4 = tid & 31;    // float4 column index within row (32 per row)
  const int rsub = tid >> 5;  // 0..7: 8 row streams per block
  const int base = blockIdx.x * rowsPerBlock;

#define DECL_ACC(K)                                                       \
  float sm##K##x = 0.f, sm##K##y = 0.f, sm##K##z = 0.f, sm##K##w = 0.f;   \
  float sq##K##x = 0.f, sq##K##y = 0.f, sq##K##z = 0.f, sq##K##w = 0.f;   \
  float ct##K = 0.f;
  DECL_ACC(0) DECL_ACC(1) DECL_ACC(2) DECL_ACC(3)
  DECL_ACC(4) DECL_ACC(5) DECL_ACC(6) DECL_ACC(7)

#define ACC1(K, v, s)                                  \
  {                                                    \
    const float ind = ((s) == K) ? 1.f : 0.f;          \
    sm##K##x = fmaf((v).x, ind, sm##K##x);             \
    sm##K##y = fmaf((v).y, ind, sm##K##y);             \
    sm##K##z = fmaf((v).z, ind, sm##K##z);             \
    sm##K##w = fmaf((v).w, ind, sm##K##w);             \
    sq##K##x = fmaf((v).x * (v).x, ind, sq##K##x);     \
    sq##K##y = fmaf((v).y * (v).y, ind, sq##K##y);     \
    sq##K##z = fmaf((v).z * (v).z, ind, sq##K##z);     \
    sq##K##w = fmaf((v).w * (v).w, ind, sq##K##w);     \
    ct##K += ind;                                      \
  }
#define ACC_ALL(v, s)                                  \
  ACC1(0, v, s) ACC1(1, v, s) ACC1(2, v, s) ACC1(3, v, s) \
  ACC1(4, v, s) ACC1(5, v, s) ACC1(6, v, s) ACC1(7, v, s)

  // 4 rows in flight per thread: r, r+8, r+16, r+24 (block covers 32 rows/iter).
  for (int r = rsub; r < rowsPerBlock; r += 32) {
    const int r0 = base + r;
    const int sA = seg[r0];
    const int sB = seg[r0 + 8];
    const int sC = seg[r0 + 16];
    const int sD = seg[r0 + 24];
    const float4 vA = x4[(size_t)r0 * (DIM / 4) + c4];
    const float4 vB = x4[(size_t)(r0 + 8) * (DIM / 4) + c4];
    const float4 vC = x4[(size_t)(r0 + 16) * (DIM / 4) + c4];
    const float4 vD = x4[(size_t)(r0 + 24) * (DIM / 4) + c4];
    ACC_ALL(vA, sA)
    ACC_ALL(vB, sB)
    ACC_ALL(vC, sC)
    ACC_ALL(vD, sD)
  }

  // -------- block-level reduce (once per block) --------
  __shared__ float ls[NDOM * DIM];
  __shared__ float lq[NDOM * DIM];
  __shared__ float lc[NDOM];
  for (int i = tid; i < NDOM * DIM; i += 256) { ls[i] = 0.f; lq[i] = 0.f; }
  if (tid < NDOM) lc[tid] = 0.f;
  __syncthreads();

  const int col = c4 * 4;
#define FLUSH(K)                                   \
  atomicAdd(&ls[K * DIM + col + 0], sm##K##x);     \
  atomicAdd(&ls[K * DIM + col + 1], sm##K##y);     \
  atomicAdd(&ls[K * DIM + col + 2], sm##K##z);     \
  atomicAdd(&ls[K * DIM + col + 3], sm##K##w);     \
  atomicAdd(&lq[K * DIM + col + 0], sq##K##x);     \
  atomicAdd(&lq[K * DIM + col + 1], sq##K##y);     \
  atomicAdd(&lq[K * DIM + col + 2], sq##K##z);     \
  atomicAdd(&lq[K * DIM + col + 3], sq##K##w);
  FLUSH(0) FLUSH(1) FLUSH(2) FLUSH(3)
  FLUSH(4) FLUSH(5) FLUSH(6) FLUSH(7)
  if (c4 == 0) {  // each row counted exactly once (by its c4==0 thread)
    atomicAdd(&lc[0], ct0); atomicAdd(&lc[1], ct1);
    atomicAdd(&lc[2], ct2); atomicAdd(&lc[3], ct3);
    atomicAdd(&lc[4], ct4); atomicAdd(&lc[5], ct5);
    atomicAdd(&lc[6], ct6); atomicAdd(&lc[7], ct7);
  }
  __syncthreads();

  float* outp = partials + (size_t)blockIdx.x * PENT;
  if (tid < NDOM) outp[tid] = lc[tid];
  for (int i = tid; i < NDOM * DIM; i += 256) {
    outp[NDOM + i] = ls[i];
    outp[NDOM + NDOM * DIM + i] = lq[i];
  }
}

// ---------------- pass 2a: reduce NB partial rows -> 64 ----------------
__global__ __launch_bounds__(256) void pn_reduce2(const float* __restrict__ partials,
                                                  float* __restrict__ partials2,
                                                  int NB) {
  const int b = blockIdx.x;  // 0..63
  const int per = NB >> 6;   // NB is pow2 >= 64
  const int b0 = b * per;
  const int tid = threadIdx.x;
  float acc[9];
#pragma unroll
  for (int i = 0; i < 9; ++i) acc[i] = 0.f;
  for (int j = b0; j < b0 + per; ++j) {
    const float* p = partials + (size_t)j * PENT;
#pragma unroll
    for (int i = 0; i < 9; ++i) {
      const int e = tid + i * 256;
      if (e < PENT) acc[i] += p[e];
    }
  }
  float* o = partials2 + (size_t)b * PENT;
#pragma unroll
  for (int i = 0; i < 9; ++i) {
    const int e = tid + i * 256;
    if (e < PENT) o[e] = acc[i];
  }
}

// ---------------- pass 2b: final reduce + scale/shift table ----------------
__global__ __launch_bounds__(1024) void pn_finalize(const float* __restrict__ partials2,
                                                    const float* __restrict__ gg,
                                                    const float* __restrict__ gb,
                                                    const float* __restrict__ dg,
                                                    const float* __restrict__ db,
                                                    float* __restrict__ stats) {
  __shared__ float cnt[NDOM];
  const int t = threadIdx.x;  // 0..1023 -> (k = t>>7, d = t&127)
  if (t < NDOM) {
    float c = 0.f;
    for (int j = 0; j < 64; ++j) c += partials2[(size_t)j * PENT + t];
    cnt[t] = fmaxf(c, 1.f);
  }
  __syncthreads();
  float s = 0.f, q = 0.f;
  for (int j = 0; j < 64; ++j) {
    const float* p = partials2 + (size_t)j * PENT;
    s += p[NDOM + t];
    q += p[NDOM + NDOM * DIM + t];
  }
  const int k = t >> 7;
  const int d = t & (DIM - 1);
  const float n = cnt[k];
  const float mean = s / n;
  const float var = fmaxf(q / n - mean * mean, 0.f);
  const float rstd = rsqrtf(var + EPSV);
  const float scale = (gg[d] + dg[t]) * rstd;  // dg[k*128+d] == dg[t]
  const float shift = (gb[d] + db[t]) - scale * mean;
  stats[t] = scale;
  stats[NDOM * DIM + t] = shift;
}

// ---------------- pass 3: normalize ----------------
__global__ __launch_bounds__(256) void pn_apply(const float* __restrict__ x,
                                                const int* __restrict__ seg,
                                                const float* __restrict__ stats,
                                                float* __restrict__ out) {
  const int g = blockIdx.x * 256 + threadIdx.x;  // float4 index
  const int row = g >> 5;                        // 32 float4 per row
  const int c4 = g & 31;
  const int s = seg[row];
  const float4 xv = ((const float4*)x)[g];
  const float4 a = ((const float4*)(stats + s * DIM))[c4];
  const float4 b = ((const float4*)(stats + NDOM * DIM + s * DIM))[c4];
  float4 o;
  o.x = fmaf(xv.x, a.x, b.x);
  o.y = fmaf(xv.y, a.y, b.y);
  o.z = fmaf(xv.z, a.z, b.z);
  o.w = fmaf(xv.w, a.w, b.w);
  ((float4*)out)[g] = o;
}

extern "C" void kernel_launch(void* const* d_in, const int* in_sizes, int n_in,
                              void* d_out, int out_size, void* d_ws, size_t ws_size,
                              hipStream_t stream) {
  const float* x = (const float*)d_in[0];
  const float* gg = (const float*)d_in[1];
  const float* gb = (const float*)d_in[2];
  const float* dg = (const float*)d_in[3];
  const float* db = (const float*)d_in[4];
  const int* seg = (const int*)d_in[5];
  float* out = (float*)d_out;

  const int B = in_sizes[5];  // 262144

  // workspace layout: partials[NB][2056] | partials2[64][2056] | stats[2048]
  int NB = 1024;
  while (NB > 64 &&
         ((size_t)NB * PENT + 64 * PENT + 2 * NDOM * DIM) * sizeof(float) > ws_size)
    NB >>= 1;
  float* partials = (float*)d_ws;
  float* partials2 = partials + (size_t)NB * PENT;
  float* stats = partials2 + (size_t)64 * PENT;

  const int rpb = B / NB;  // B = 2^18, NB pow2 -> exact, multiple of 32

  pn_reduce<<<NB, 256, 0, stream>>>((const float4*)x, seg, partials, rpb);
  pn_reduce2<<<64, 256, 0, stream>>>(partials, partials2, NB);
  pn_finalize<<<1, 1024, 0, stream>>>(partials2, gg, gb, dg, db, stats);

  const int nblk = (B * (DIM / 4)) / 256;  // 32768
  pn_apply<<<nblk, 256, 0, stream>>>(x, seg, stats, out);
}

// Round 6
// 131.982 us; speedup vs baseline: 3.1308x; 1.3226x over previous
//
#include <hip/hip_runtime.h>
#include <hip/hip_bf16.h>

// PartitionedNormalization: per-domain BN stats (training mode) + affine.
// out[B][128] f32 = (gg+dg[s])*(x-mean[s])*rsqrt(var[s]+eps) + (gb+db[s])

#define DIM 128
#define NDOM 8
#define PENT (NDOM + 2 * NDOM * DIM)  // 8 counts + 1024 sums + 1024 sqsums = 2056
#define EPSV 1e-3f
#define WREG 2080  // per-wave LDS region (floats): 1024 sum + 1024 sq + 8 cnt + pad

// ---------------- pass 1: wave-private LDS accumulation ----------------
// One WAVE processes one row per iteration: 64 lanes x float2 = 128 cols.
// Accumulate into a per-wave LDS region at [s*128 + col] -- plain RMW,
// no atomics (all 64 lanes hit distinct addresses; regions are wave-private),
// no barriers in the main loop, no indicator fan-out, ~32 VGPR.
// (R4/R5 lesson: 72 register accumulators + 8-way cndmask chains left every
// pipe <15% busy at 27% occupancy -- structure was latency-bound, 6x off floor.)
__global__ __launch_bounds__(256, 4) void pn_reduce(const float2* __restrict__ x2,
                                                    const int* __restrict__ seg,
                                                    float* __restrict__ partials,
                                                    int rowsPerBlock) {
  __shared__ float acc[4 * WREG];
  const int tid = threadIdx.x;
  const int w = tid >> 6;  // wave id 0..3
  const int l = tid & 63;  // lane id
  float* reg = acc + w * WREG;

  for (int i = tid; i < 4 * WREG; i += 256) acc[i] = 0.f;
  __syncthreads();

  const int base = blockIdx.x * rowsPerBlock;
  for (int it = 0; it < rowsPerBlock; it += 4) {
    const int row = base + it + w;            // each wave: every 4th row
    const int s = seg[row];                   // uniform across the wave
    const float2 v = x2[(size_t)row * (DIM / 2) + l];
    float* ps = reg + s * DIM + l * 2;        // sum slot (8B aligned)
    float* pq = ps + NDOM * DIM;              // sq slot
    float2 os = *(float2*)ps;
    os.x += v.x;
    os.y += v.y;
    *(float2*)ps = os;
    float2 oq = *(float2*)pq;
    oq.x = fmaf(v.x, v.x, oq.x);
    oq.y = fmaf(v.y, v.y, oq.y);
    *(float2*)pq = oq;
    if (l == 0) reg[2 * NDOM * DIM + s] += 1.f;  // count row once
  }
  __syncthreads();

  // combine the 4 wave regions -> partials[block][PENT]
  float* outp = partials + (size_t)blockIdx.x * PENT;
  if (tid < NDOM) {
    float c = 0.f;
#pragma unroll
    for (int ww = 0; ww < 4; ++ww) c += acc[ww * WREG + 2 * NDOM * DIM + tid];
    outp[tid] = c;
  }
  for (int i = tid; i < 2 * NDOM * DIM; i += 256) {
    float v = 0.f;
#pragma unroll
    for (int ww = 0; ww < 4; ++ww) v += acc[ww * WREG + i];
    outp[NDOM + i] = v;
  }
}

// ---------------- pass 2a: reduce NB partial rows -> 64 ----------------
__global__ __launch_bounds__(256) void pn_reduce2(const float* __restrict__ partials,
                                                  float* __restrict__ partials2,
                                                  int NB) {
  const int b = blockIdx.x;  // 0..63
  const int per = NB >> 6;   // NB is pow2 >= 64
  const int b0 = b * per;
  const int tid = threadIdx.x;
  float acc[9];
#pragma unroll
  for (int i = 0; i < 9; ++i) acc[i] = 0.f;
  for (int j = b0; j < b0 + per; ++j) {
    const float* p = partials + (size_t)j * PENT;
#pragma unroll
    for (int i = 0; i < 9; ++i) {
      const int e = tid + i * 256;
      if (e < PENT) acc[i] += p[e];
    }
  }
  float* o = partials2 + (size_t)b * PENT;
#pragma unroll
  for (int i = 0; i < 9; ++i) {
    const int e = tid + i * 256;
    if (e < PENT) o[e] = acc[i];
  }
}

// ---------------- pass 2b: final reduce + scale/shift table ----------------
__global__ __launch_bounds__(1024) void pn_finalize(const float* __restrict__ partials2,
                                                    const float* __restrict__ gg,
                                                    const float* __restrict__ gb,
                                                    const float* __restrict__ dg,
                                                    const float* __restrict__ db,
                                                    float* __restrict__ stats) {
  __shared__ float cnt[NDOM];
  const int t = threadIdx.x;  // 0..1023 -> (k = t>>7, d = t&127)
  if (t < NDOM) {
    float c = 0.f;
    for (int j = 0; j < 64; ++j) c += partials2[(size_t)j * PENT + t];
    cnt[t] = fmaxf(c, 1.f);
  }
  __syncthreads();
  float s = 0.f, q = 0.f;
  for (int j = 0; j < 64; ++j) {
    const float* p = partials2 + (size_t)j * PENT;
    s += p[NDOM + t];
    q += p[NDOM + NDOM * DIM + t];
  }
  const int k = t >> 7;
  const int d = t & (DIM - 1);
  const float n = cnt[k];
  const float mean = s / n;
  const float var = fmaxf(q / n - mean * mean, 0.f);
  const float rstd = rsqrtf(var + EPSV);
  const float scale = (gg[d] + dg[t]) * rstd;  // dg[k*128+d] == dg[t]
  const float shift = (gb[d] + db[t]) - scale * mean;
  stats[t] = scale;
  stats[NDOM * DIM + t] = shift;
}

// ---------------- pass 3: normalize (at roofline, unchanged) ----------------
__global__ __launch_bounds__(256) void pn_apply(const float* __restrict__ x,
                                                const int* __restrict__ seg,
                                                const float* __restrict__ stats,
                                                float* __restrict__ out) {
  const int g = blockIdx.x * 256 + threadIdx.x;  // float4 index
  const int row = g >> 5;                        // 32 float4 per row
  const int c4 = g & 31;
  const int s = seg[row];
  const float4 xv = ((const float4*)x)[g];
  const float4 a = ((const float4*)(stats + s * DIM))[c4];
  const float4 b = ((const float4*)(stats + NDOM * DIM + s * DIM))[c4];
  float4 o;
  o.x = fmaf(xv.x, a.x, b.x);
  o.y = fmaf(xv.y, a.y, b.y);
  o.z = fmaf(xv.z, a.z, b.z);
  o.w = fmaf(xv.w, a.w, b.w);
  ((float4*)out)[g] = o;
}

extern "C" void kernel_launch(void* const* d_in, const int* in_sizes, int n_in,
                              void* d_out, int out_size, void* d_ws, size_t ws_size,
                              hipStream_t stream) {
  const float* x = (const float*)d_in[0];
  const float* gg = (const float*)d_in[1];
  const float* gb = (const float*)d_in[2];
  const float* dg = (const float*)d_in[3];
  const float* db = (const float*)d_in[4];
  const int* seg = (const int*)d_in[5];
  float* out = (float*)d_out;

  const int B = in_sizes[5];  // 262144

  // workspace layout: partials[NB][2056] | partials2[64][2056] | stats[2048]
  int NB = 2048;
  while (NB > 64 &&
         ((size_t)NB * PENT + 64 * PENT + 2 * NDOM * DIM) * sizeof(float) > ws_size)
    NB >>= 1;
  float* partials = (float*)d_ws;
  float* partials2 = partials + (size_t)NB * PENT;
  float* stats = partials2 + (size_t)64 * PENT;

  const int rpb = B / NB;  // B = 2^18, NB pow2 -> exact, multiple of 4

  pn_reduce<<<NB, 256, 0, stream>>>((const float2*)x, seg, partials, rpb);
  pn_reduce2<<<64, 256, 0, stream>>>(partials, partials2, NB);
  pn_finalize<<<1, 1024, 0, stream>>>(partials2, gg, gb, dg, db, stats);

  const int nblk = (B * (DIM / 4)) / 256;  // 32768
  pn_apply<<<nblk, 256, 0, stream>>>(x, seg, stats, out);
}

// Round 7
// 103.688 us; speedup vs baseline: 3.9851x; 1.2729x over previous
//
#include <hip/hip_runtime.h>
#include <hip/hip_bf16.h>

// PartitionedNormalization: per-domain BN stats (training mode) + affine.
// out[B][128] f32 = (gg+dg[s])*(x-mean[s])*rsqrt(var[s]+eps) + (gb+db[s])

#define DIM 128
#define NDOM 8
#define PENT (NDOM + 2 * NDOM * DIM)  // 8 counts + 1024 sums + 1024 sqsums = 2056
#define EPSV 1e-3f
// per-wave LDS region (floats): [8 dom][64 lanes][4: smx,smy,sqx,sqy] + 8 cnt
#define WR 2056

// ---------------- pass 1: wave-private LDS accumulation, b128 RMW ----------------
// One WAVE processes one row per iteration: 64 lanes x float2 = 128 cols.
// sum/sq interleaved in ONE 16B slot per lane -> 1 ds_read_b128 + 1 ds_write_b128
// per row (R6 had 2+2 b64). Lane addr = l*16 contiguous: conflict-free (m134).
// Waves own contiguous 64-row chunks -> seg prefetched as int4 per 4 rows.
// Wave-private regions + in-order per-wave DS pipe -> no atomics, no barriers.
__global__ __launch_bounds__(256, 4) void pn_reduce(const float2* __restrict__ x2,
                                                    const int* __restrict__ seg,
                                                    float* __restrict__ partials,
                                                    int rowsPerBlock) {
  __shared__ float acc[4 * WR];
  const int tid = threadIdx.x;
  const int w = tid >> 6;  // wave id 0..3
  const int l = tid & 63;  // lane id
  float* reg = acc + w * WR;

  for (int i = tid; i < 4 * WR; i += 256) acc[i] = 0.f;
  __syncthreads();

  const int rowsPerWave = rowsPerBlock >> 2;
  const int row0 = blockIdx.x * rowsPerBlock + w * rowsPerWave;

  for (int it = 0; it < rowsPerWave; it += 4) {
    const int4 sg = *(const int4*)(seg + row0 + it);  // 4 rows' domains (16B aligned)
    // load 4 rows up front (independent addresses -> pipelined)
    const float2 vA = x2[(size_t)(row0 + it + 0) * (DIM / 2) + l];
    const float2 vB = x2[(size_t)(row0 + it + 1) * (DIM / 2) + l];
    const float2 vC = x2[(size_t)(row0 + it + 2) * (DIM / 2) + l];
    const float2 vD = x2[(size_t)(row0 + it + 3) * (DIM / 2) + l];
#define RMW(S, V)                                            \
  {                                                          \
    float4* slot = (float4*)(reg + (S)*256 + l * 4);         \
    float4 o = *slot;                                        \
    o.x += (V).x;                                            \
    o.y += (V).y;                                            \
    o.z = fmaf((V).x, (V).x, o.z);                           \
    o.w = fmaf((V).y, (V).y, o.w);                           \
    *slot = o;                                               \
    if (l == 0) reg[2048 + (S)] += 1.f;                      \
  }
    RMW(sg.x, vA)
    RMW(sg.y, vB)
    RMW(sg.z, vC)
    RMW(sg.w, vD)
#undef RMW
  }
  __syncthreads();

  // combine the 4 wave regions -> partials[block][PENT] (counts | sums | sqs)
  float* outp = partials + (size_t)blockIdx.x * PENT;
  if (tid < NDOM) {
    float c = 0.f;
#pragma unroll
    for (int ww = 0; ww < 4; ++ww) c += acc[ww * WR + 2048 + tid];
    outp[tid] = c;
  }
  for (int i = tid; i < 2 * NDOM * DIM; i += 256) {
    const int isq = i >> 10;   // 0 = sum, 1 = sq
    const int j = i & 1023;    // (s, col)
    const int s = j >> 7;
    const int col = j & 127;
    const int off = s * 256 + (col >> 1) * 4 + isq * 2 + (col & 1);
    float v = 0.f;
#pragma unroll
    for (int ww = 0; ww < 4; ++ww) v += acc[ww * WR + off];
    outp[NDOM + i] = v;
  }
}

// ---------------- pass 2a: reduce NB partial rows -> 64 ----------------
__global__ __launch_bounds__(256) void pn_reduce2(const float* __restrict__ partials,
                                                  float* __restrict__ partials2,
                                                  int NB) {
  const int b = blockIdx.x;  // 0..63
  const int per = NB >> 6;   // NB is pow2 >= 64
  const int b0 = b * per;
  const int tid = threadIdx.x;
  float acc[9];
#pragma unroll
  for (int i = 0; i < 9; ++i) acc[i] = 0.f;
  for (int j = b0; j < b0 + per; ++j) {
    const float* p = partials + (size_t)j * PENT;
#pragma unroll
    for (int i = 0; i < 9; ++i) {
      const int e = tid + i * 256;
      if (e < PENT) acc[i] += p[e];
    }
  }
  float* o = partials2 + (size_t)b * PENT;
#pragma unroll
  for (int i = 0; i < 9; ++i) {
    const int e = tid + i * 256;
    if (e < PENT) o[e] = acc[i];
  }
}

// ---------------- pass 2b: final reduce + scale/shift table ----------------
__global__ __launch_bounds__(1024) void pn_finalize(const float* __restrict__ partials2,
                                                    const float* __restrict__ gg,
                                                    const float* __restrict__ gb,
                                                    const float* __restrict__ dg,
                                                    const float* __restrict__ db,
                                                    float* __restrict__ stats) {
  __shared__ float cnt[NDOM];
  const int t = threadIdx.x;  // 0..1023 -> (k = t>>7, d = t&127)
  if (t < NDOM) {
    float c = 0.f;
    for (int j = 0; j < 64; ++j) c += partials2[(size_t)j * PENT + t];
    cnt[t] = fmaxf(c, 1.f);
  }
  __syncthreads();
  float s = 0.f, q = 0.f;
  for (int j = 0; j < 64; ++j) {
    const float* p = partials2 + (size_t)j * PENT;
    s += p[NDOM + t];
    q += p[NDOM + NDOM * DIM + t];
  }
  const int k = t >> 7;
  const int d = t & (DIM - 1);
  const float n = cnt[k];
  const float mean = s / n;
  const float var = fmaxf(q / n - mean * mean, 0.f);
  const float rstd = rsqrtf(var + EPSV);
  const float scale = (gg[d] + dg[t]) * rstd;  // dg[k*128+d] == dg[t]
  const float shift = (gb[d] + db[t]) - scale * mean;
  stats[t] = scale;
  stats[NDOM * DIM + t] = shift;
}

// ---------------- pass 3: normalize (at roofline, unchanged) ----------------
__global__ __launch_bounds__(256) void pn_apply(const float* __restrict__ x,
                                                const int* __restrict__ seg,
                                                const float* __restrict__ stats,
                                                float* __restrict__ out) {
  const int g = blockIdx.x * 256 + threadIdx.x;  // float4 index
  const int row = g >> 5;                        // 32 float4 per row
  const int c4 = g & 31;
  const int s = seg[row];
  const float4 xv = ((const float4*)x)[g];
  const float4 a = ((const float4*)(stats + s * DIM))[c4];
  const float4 b = ((const float4*)(stats + NDOM * DIM + s * DIM))[c4];
  float4 o;
  o.x = fmaf(xv.x, a.x, b.x);
  o.y = fmaf(xv.y, a.y, b.y);
  o.z = fmaf(xv.z, a.z, b.z);
  o.w = fmaf(xv.w, a.w, b.w);
  ((float4*)out)[g] = o;
}

extern "C" void kernel_launch(void* const* d_in, const int* in_sizes, int n_in,
                              void* d_out, int out_size, void* d_ws, size_t ws_size,
                              hipStream_t stream) {
  const float* x = (const float*)d_in[0];
  const float* gg = (const float*)d_in[1];
  const float* gb = (const float*)d_in[2];
  const float* dg = (const float*)d_in[3];
  const float* db = (const float*)d_in[4];
  const int* seg = (const int*)d_in[5];
  float* out = (float*)d_out;

  const int B = in_sizes[5];  // 262144

  // workspace layout: partials[NB][2056] | partials2[64][2056] | stats[2048]
  int NB = 1024;  // exactly 4 blocks/CU, one dispatch round
  while (NB > 64 &&
         ((size_t)NB * PENT + 64 * PENT + 2 * NDOM * DIM) * sizeof(float) > ws_size)
    NB >>= 1;
  float* partials = (float*)d_ws;
  float* partials2 = partials + (size_t)NB * PENT;
  float* stats = partials2 + (size_t)64 * PENT;

  const int rpb = B / NB;  // 256; per wave 64 contiguous rows

  pn_reduce<<<NB, 256, 0, stream>>>((const float2*)x, seg, partials, rpb);
  pn_reduce2<<<64, 256, 0, stream>>>(partials, partials2, NB);
  pn_finalize<<<1, 1024, 0, stream>>>(partials2, gg, gb, dg, db, stats);

  const int nblk = (B * (DIM / 4)) / 256;  // 32768
  pn_apply<<<nblk, 256, 0, stream>>>(x, seg, stats, out);
}